// Round 11
// baseline (9109.892 us; speedup 1.0000x reference)
//
#include <hip/hip_runtime.h>
#include <math.h>

#define H        1024
#define TSTEPS   2048
#define NWG      64
#define NT       1024
#define PAD      68            // padded segment stride (floats): 0-conflict (R5)
#define SENT     0xFFFFFFFFu   // -NaN bit pattern: h can never be this

typedef unsigned u32x4 __attribute__((ext_vector_type(4)));
typedef float    f32x2 __attribute__((ext_vector_type(2)));
typedef float    f32x4 __attribute__((ext_vector_type(4)));

// AGENT-scope loads: load + waitcnt in ONE asm block (R8 lesson: splitting
// them lets the compiler read in-flight registers).
__device__ __forceinline__ u32x4 load16_agent(const unsigned* p) {
    u32x4 r;
    asm volatile("global_load_dwordx4 %0, %1, off sc1\n\ts_waitcnt vmcnt(0)"
                 : "=v"(r) : "v"(p) : "memory");
    return r;
}
__device__ __forceinline__ unsigned load4_agent(const unsigned* p) {
    unsigned r;
    asm volatile("global_load_dword %0, %1, off sc1\n\ts_waitcnt vmcnt(0)"
                 : "=v"(r) : "v"(p) : "memory");
    return r;
}

// Packed FP32 FMA (VOP3P): 2 FMAs/instruction (R10-proven).
__device__ __forceinline__ void pkfma(f32x2& acc, f32x2 a, f32x2 b) {
    asm("v_pk_fma_f32 %0, %1, %2, %0" : "+v"(acc) : "v"(a), "v"(b));
}

__device__ __forceinline__ float fsig(float x)   { return 1.0f / (1.0f + __expf(-x)); }
__device__ __forceinline__ float ftanh_(float x) { return 1.0f - 2.0f / (__expf(2.0f * x) + 1.0f); }

__device__ __forceinline__ bool ok4(u32x4 v) {
    return v.x != SENT && v.y != SENT && v.z != SENT && v.w != SENT;
}

__global__ __launch_bounds__(NT, 1) void lstm_persistent(
    const float* __restrict__ z,   const float* __restrict__ Wih,
    const float* __restrict__ Whh, const float* __restrict__ b_ih,
    const float* __restrict__ b_hh,
    const float* __restrict__ W1,  const float* __restrict__ b1,
    const float* __restrict__ W2,  const float* __restrict__ b2,
    const float* __restrict__ W3,  const float* __restrict__ b3,
    float* __restrict__ out, float* __restrict__ hs, unsigned* __restrict__ cnt)
{
    __shared__ __align__(16) float hbuf[2][16 * PAD];   // double-buffered h row
    __shared__ unsigned h_out[2][16];                   // per-wave h handoff
    __shared__ __align__(16) float mlp_buf[4][16 * PAD];
    __shared__ float a1_lds[4][32];
    __shared__ float a2_lds[4][32];

    const int tid  = threadIdx.x;
    const int wg   = blockIdx.x;
    const int wave = tid >> 6;       // wave w owns element E = wg*16 + w
    const int lane = tid & 63;
    const int g    = lane >> 4;      // gate 0=i,1=f,2=g,3=o
    const int seg  = lane & 15;      // 64-col segment
    const int E    = wg * 16 + wave;
    const int grow = g * H + E;
    const float bias = b_ih[grow] + b_hh[grow];

    if (tid < 32) h_out[tid >> 4][tid & 15] = SENT;

    // ---- stage z -> hbuf[0] ----
    if (tid < 256) {
        float4 zv = *(const float4*)(z + tid * 4);
        *(float4*)(&hbuf[0][(tid >> 4) * PAD + (tid & 15) * 4]) = zv;
    }
    __syncthreads();

    // ---- weights (Wc = Wih+Whh) into regs; fused step-0 dot (x=z, h=c=0) ----
    f32x4 wreg[16];
    float s0 = 0.f, s1 = 0.f, s2 = 0.f, s3 = 0.f;
    const float* wihp = Wih + (size_t)grow * H + seg * 64;
    const float* whhp = Whh + (size_t)grow * H + seg * 64;
#pragma unroll
    for (int k = 0; k < 16; ++k) {
        f32x4 a  = *(const f32x4*)(wihp + 4 * k);
        f32x4 b  = *(const f32x4*)(whhp + 4 * k);
        f32x4 zz = *(const f32x4*)(&hbuf[0][seg * PAD + 4 * k]);
        float d = a.x * zz.x + a.y * zz.y + a.z * zz.z + a.w * zz.w;
        if ((k & 3) == 0) s0 += d; else if ((k & 3) == 1) s1 += d;
        else if ((k & 3) == 2) s2 += d; else s3 += d;
        wreg[k] = a + b;
    }
    float c_reg;   // replicated across all lanes of the wave (uniform)
    {
        float acc = (s0 + s1) + (s2 + s3);
        acc += __shfl_xor(acc, 1); acc += __shfl_xor(acc, 2);
        acc += __shfl_xor(acc, 4); acc += __shfl_xor(acc, 8);
        float val = acc + bias;
        float act = (g == 2) ? ftanh_(val) : fsig(val);   // parallel nonlinearity
        float si = __shfl(act, 0), tg = __shfl(act, 32), so = __shfl(act, 48);
        c_reg = si * tg;                                  // c_prev = 0
        float hn = so * ftanh_(c_reg);
        if (lane == 0) ((volatile unsigned*)h_out[0])[wave] = __float_as_uint(hn);
        if (wave == 15) {
            unsigned v;
            do { v = ((volatile unsigned*)h_out[0])[lane & 15]; } while (!__all(v != SENT));
            if (lane < 16) {
                __hip_atomic_store((unsigned*)hs + wg * 16 + lane, v,
                                   __ATOMIC_RELAXED, __HIP_MEMORY_SCOPE_AGENT);
                ((volatile unsigned*)h_out[0])[lane] = SENT;
                hbuf[1][(wg >> 2) * PAD + ((wg * 16) & 63) + lane] = __uint_as_float(v);
            }
            if (lane == 0)   // completion signal (no ack-wait; sentinels backstop)
                __hip_atomic_fetch_add(cnt + (size_t)(0 * 4 + (wg & 3)) * 16, 1u,
                                       __ATOMIC_RELAXED, __HIP_MEMORY_SCOPE_AGENT);
        }
    }

    // ---- main recurrence: ONE barrier per step ----
    for (int t = 1; t < TSTEPS; ++t) {
        const int q = t & 1;
        if (tid < 256 && (tid >> 2) != wg) {   // pollers (waves 0-3), skip own chunk
            const unsigned* p = (const unsigned*)hs + (size_t)(t - 1) * H + tid * 4;
            u32x4 v = load16_agent(p);         // speculative first try (free if ready)
            if (!ok4(v)) {
                // cheap wait: 4 counter lines instead of 63 data lines
                const unsigned* cp = cnt + ((size_t)(t - 1) * 4 + (lane & 3)) * 16;
                unsigned cv;
                do { cv = load4_agent(cp); } while (!__all(cv == 16u));
                for (;;) {                     // fetch + sentinel backstop
                    v = load16_agent(p);
                    if (ok4(v)) break;
                }
            }
            float* dst = &hbuf[q][(tid >> 4) * PAD + (tid & 15) * 4];
            dst[0] = __uint_as_float(v.x); dst[1] = __uint_as_float(v.y);
            dst[2] = __uint_as_float(v.z); dst[3] = __uint_as_float(v.w);
        }
        __syncthreads();                       // B1: row t-1 staged

        const float* hb = &hbuf[q][seg * PAD];
        f32x2 p0 = {0.f, 0.f}, p1 = {0.f, 0.f}, p2 = {0.f, 0.f}, p3 = {0.f, 0.f};
#pragma unroll
        for (int k = 0; k < 16; ++k) {
            f32x4 h4 = *(const f32x4*)(hb + 4 * k);
            f32x4 wv = wreg[k];
            if ((k & 1) == 0) { pkfma(p0, wv.xy, h4.xy); pkfma(p1, wv.zw, h4.zw); }
            else              { pkfma(p2, wv.xy, h4.xy); pkfma(p3, wv.zw, h4.zw); }
        }
        f32x2 ps = (p0 + p1) + (p2 + p3);
        float a2 = ps.x + ps.y;
        a2 += __shfl_xor(a2, 1); a2 += __shfl_xor(a2, 2);
        a2 += __shfl_xor(a2, 4); a2 += __shfl_xor(a2, 8);
        float val = a2 + bias;
        float act = (g == 2) ? ftanh_(val) : fsig(val);   // parallel nonlinearity
        float si = __shfl(act, 0),  sf = __shfl(act, 16);
        float tg = __shfl(act, 32), so = __shfl(act, 48);
        float cn = sf * c_reg + si * tg;                  // wave-uniform cell
        float hn = so * ftanh_(cn);
        c_reg = cn;
        if (lane == 0) ((volatile unsigned*)h_out[q])[wave] = __float_as_uint(hn);
        if (wave == 15) {                      // gather + coalesced 64B store
            unsigned v;
            do { v = ((volatile unsigned*)h_out[q])[lane & 15]; } while (!__all(v != SENT));
            if (lane < 16) {
                __hip_atomic_store((unsigned*)(hs + (size_t)t * H) + wg * 16 + lane, v,
                                   __ATOMIC_RELAXED, __HIP_MEMORY_SCOPE_AGENT);
                ((volatile unsigned*)h_out[q])[lane] = SENT;   // reset for t+2
                hbuf[q ^ 1][(wg >> 2) * PAD + ((wg * 16) & 63) + lane] =
                    __uint_as_float(v);        // self-copy: skip own poll at t+1
            }
            if (lane == 0)   // completion signal for row t
                __hip_atomic_fetch_add(cnt + ((size_t)t * 4 + (wg & 3)) * 16, 1u,
                                       __ATOMIC_RELAXED, __HIP_MEMORY_SCOPE_AGENT);
        }
    }

    // ---- MLP tail: 4 groups x 256 threads (R5-proven, serial 16B polls) ----
    const int local = tid & 255;
    const int grp   = tid >> 8;      // 0..3
    const int row32 = local >> 3;    // 0..31
    const int sub   = local & 7;     // 0..7
    for (int ti = 0; ti < 8; ++ti) {
        int t = wg * 32 + ti * 4 + grp;
        __syncthreads();                       // WAR: prior mlp_buf/a_lds use
        {
            const unsigned* p = (const unsigned*)hs + (size_t)t * H + local * 4;
            u32x4 v;
            for (;;) {
                v = load16_agent(p);
                if (ok4(v)) break;
            }
            float* dst = &mlp_buf[grp][(local >> 4) * PAD + (local & 15) * 4];
            dst[0] = __uint_as_float(v.x); dst[1] = __uint_as_float(v.y);
            dst[2] = __uint_as_float(v.z); dst[3] = __uint_as_float(v.w);
        }
        __syncthreads();                       // row staged

        float acc1 = 0.f;
        const float* w1p = W1 + (size_t)row32 * H + sub * 128;
#pragma unroll
        for (int k = 0; k < 32; ++k) {
            float4 wv = *(const float4*)(w1p + 4 * k);
            int c = sub * 128 + 4 * k;
            float4 h4 = *(const float4*)(&mlp_buf[grp][(c >> 6) * PAD + (c & 63)]);
            acc1 += wv.x * h4.x + wv.y * h4.y + wv.z * h4.z + wv.w * h4.w;
        }
        acc1 += __shfl_xor(acc1, 1); acc1 += __shfl_xor(acc1, 2); acc1 += __shfl_xor(acc1, 4);
        if (sub == 0) a1_lds[grp][row32] = fmaxf(acc1 + b1[row32], 0.f);
        __syncthreads();                       // a1 ready

        if (local < 32) {
            float a = 0.f;
#pragma unroll
            for (int k = 0; k < 32; ++k) a += W2[local * 32 + k] * a1_lds[grp][k];
            a2_lds[grp][local] = fmaxf(a + b2[local], 0.f);
        }
        __syncthreads();                       // a2 ready

        if (local < 64) {
            float a = 0.f;
#pragma unroll
            for (int k = 0; k < 32; ++k) a += W3[local * 32 + k] * a2_lds[grp][k];
            out[(size_t)t * 64 + local] = a + b3[local];
        }
    }
}

extern "C" void kernel_launch(void* const* d_in, const int* in_sizes, int n_in,
                              void* d_out, int out_size, void* d_ws, size_t ws_size,
                              hipStream_t stream) {
    const float* z    = (const float*)d_in[0];
    const float* Wih  = (const float*)d_in[1];
    const float* Whh  = (const float*)d_in[2];
    const float* b_ih = (const float*)d_in[3];
    const float* b_hh = (const float*)d_in[4];
    const float* W1   = (const float*)d_in[5];
    const float* b1   = (const float*)d_in[6];
    const float* W2   = (const float*)d_in[7];
    const float* b2   = (const float*)d_in[8];
    const float* W3   = (const float*)d_in[9];
    const float* b3   = (const float*)d_in[10];
    float* out = (float*)d_out;

    float*    hs  = (float*)d_ws;                       // 8 MB: TSTEPS*H floats
    unsigned* cnt = (unsigned*)((char*)d_ws + (size_t)TSTEPS * H * sizeof(float));
    // cnt: TSTEPS * 4 sub-counters, 64B apart = 512 KB

    hipMemsetAsync(hs, 0xFF, (size_t)TSTEPS * H * sizeof(float), stream);
    hipMemsetAsync(cnt, 0, (size_t)TSTEPS * 4 * 16 * sizeof(unsigned), stream);
    hipLaunchKernelGGL(lstm_persistent, dim3(NWG), dim3(NT), 0, stream,
                       z, Wih, Whh, b_ih, b_hh, W1, b1, W2, b2, W3, b3,
                       out, hs, cnt);
}

// Round 12
// 4267.834 us; speedup vs baseline: 2.1345x; 2.1345x over previous
//
#include <hip/hip_runtime.h>
#include <math.h>

#define H        1024
#define TSTEPS   2048
#define NWG      64
#define NT       1024
#define PAD      68            // padded segment stride (floats): 0-conflict (R5)
#define SENT     0xFFFFFFFFu   // -NaN bit pattern: h can never be this

typedef unsigned u32x4 __attribute__((ext_vector_type(4)));
typedef float    f32x2 __attribute__((ext_vector_type(2)));
typedef float    f32x4 __attribute__((ext_vector_type(4)));
typedef unsigned long long u64;

// 16B AGENT-scope load, load+waitcnt in ONE asm block (R5/R9-proven).
__device__ __forceinline__ u32x4 load16_agent(const unsigned* p) {
    u32x4 r;
    asm volatile("global_load_dwordx4 %0, %1, off sc1\n\ts_waitcnt vmcnt(0)"
                 : "=v"(r) : "v"(p) : "memory");
    return r;
}

// Packed FP32 FMA (VOP3P): 2 FMAs/instruction (R10-proven mechanically).
__device__ __forceinline__ void pkfma(f32x2& acc, f32x2 a, f32x2 b) {
    asm("v_pk_fma_f32 %0, %1, %2, %0" : "+v"(acc) : "v"(a), "v"(b));
}

__device__ __forceinline__ float fsig(float x)   { return 1.0f / (1.0f + __expf(-x)); }
__device__ __forceinline__ float ftanh_(float x) { return 1.0f - 2.0f / (__expf(2.0f * x) + 1.0f); }

__device__ __forceinline__ bool ok4(u32x4 v) {
    return v.x != SENT && v.y != SENT && v.z != SENT && v.w != SENT;
}

__global__ __launch_bounds__(NT, 1) void lstm_persistent(
    const float* __restrict__ z,   const float* __restrict__ Wih,
    const float* __restrict__ Whh, const float* __restrict__ b_ih,
    const float* __restrict__ b_hh,
    const float* __restrict__ W1,  const float* __restrict__ b1,
    const float* __restrict__ W2,  const float* __restrict__ b2,
    const float* __restrict__ W3,  const float* __restrict__ b3,
    float* __restrict__ out, float* __restrict__ hs)
{
    __shared__ __align__(16) float hbuf[2][16 * PAD];   // double-buffered h row
    __shared__ unsigned h_out[2][16];                   // per-wave h handoff
    __shared__ __align__(16) float mlp_buf[4][16 * PAD];
    __shared__ float a1_lds[4][32];
    __shared__ float a2_lds[4][32];

    const int tid  = threadIdx.x;
    const int wg   = blockIdx.x;
    const int wave = tid >> 6;       // wave w owns element E = wg*16 + w
    const int lane = tid & 63;
    const int g    = lane >> 4;      // gate 0=i,1=f,2=g,3=o
    const int seg  = lane & 15;      // 64-col segment
    const int E    = wg * 16 + wave;
    const int grow = g * H + E;
    const float bias = b_ih[grow] + b_hh[grow];

    if (tid < 32) h_out[tid >> 4][tid & 15] = SENT;

    // ---- stage z -> hbuf[0] ----
    if (tid < 256) {
        float4 zv = *(const float4*)(z + tid * 4);
        *(float4*)(&hbuf[0][(tid >> 4) * PAD + (tid & 15) * 4]) = zv;
    }
    __syncthreads();

    // ---- weights (Wc = Wih+Whh) into regs; fused step-0 dot (x=z, h=c=0) ----
    f32x4 wreg[16];
    float s0 = 0.f, s1 = 0.f, s2 = 0.f, s3 = 0.f;
    const float* wihp = Wih + (size_t)grow * H + seg * 64;
    const float* whhp = Whh + (size_t)grow * H + seg * 64;
#pragma unroll
    for (int k = 0; k < 16; ++k) {
        f32x4 a  = *(const f32x4*)(wihp + 4 * k);
        f32x4 b  = *(const f32x4*)(whhp + 4 * k);
        f32x4 zz = *(const f32x4*)(&hbuf[0][seg * PAD + 4 * k]);
        float d = a.x * zz.x + a.y * zz.y + a.z * zz.z + a.w * zz.w;
        if ((k & 3) == 0) s0 += d; else if ((k & 3) == 1) s1 += d;
        else if ((k & 3) == 2) s2 += d; else s3 += d;
        wreg[k] = a + b;
    }
    float c_reg;   // replicated across all lanes of the wave (uniform)
    {
        float acc = (s0 + s1) + (s2 + s3);
        acc += __shfl_xor(acc, 1); acc += __shfl_xor(acc, 2);
        acc += __shfl_xor(acc, 4); acc += __shfl_xor(acc, 8);
        float val = acc + bias;
        float act = (g == 2) ? ftanh_(val) : fsig(val);   // parallel nonlinearity
        float si = __shfl(act, 0), tg = __shfl(act, 32), so = __shfl(act, 48);
        c_reg = si * tg;                                  // c_prev = 0
        float hn = so * ftanh_(c_reg);
        if (lane == 0) ((volatile unsigned*)h_out[0])[wave] = __float_as_uint(hn);
        if (wave == 15) {
            unsigned v;
            do { v = ((volatile unsigned*)h_out[0])[lane & 15]; } while (!__all(v != SENT));
            if (lane < 16) {
                __hip_atomic_store((unsigned*)hs + wg * 16 + lane, v,
                                   __ATOMIC_RELAXED, __HIP_MEMORY_SCOPE_AGENT);
                ((volatile unsigned*)h_out[0])[lane] = SENT;
                hbuf[1][(wg >> 2) * PAD + ((wg * 16) & 63) + lane] = __uint_as_float(v);
            }
        }
    }

    // Persistent 2-slot poll registers: pending loads land into these across
    // steps; NO vmcnt drain inside the loop (the drain was R10's hidden cost).
    u64 pa = 0, pb = 0;

    // ---- main recurrence: ONE barrier per step ----
    for (int t = 1; t < TSTEPS; ++t) {
        const int q = t & 1;
        if (tid < 512 && (tid >> 3) != wg) {   // pollers: waves 0-7, 8B each, skip own
            const unsigned* p = (const unsigned*)hs + (size_t)(t - 1) * H + tid * 2;
            const int e2 = tid * 2;
            unsigned dst = (unsigned)(size_t)&hbuf[q][(e2 >> 6) * PAD + (e2 & 63)];
            // 2-slot pipelined sc1 poll, detect-quantum ~RT/2, stage via
            // ds_write inside asm, exit WITHOUT draining the other slot.
            asm volatile(
                "global_load_dwordx2 %0, %2, off sc1\n\t"
                "s_sleep 8\n\t"
                "global_load_dwordx2 %1, %2, off sc1\n\t"
                "1:\n\t"
                "s_waitcnt vmcnt(1)\n\t"               // slot A landed
                "v_cmp_eq_u64 vcc, -1, %0\n\t"
                "s_cbranch_vccz 2f\n\t"                 // no lane all-SENT -> A ready
                "global_load_dwordx2 %0, %2, off sc1\n\t"
                "s_waitcnt vmcnt(1)\n\t"               // slot B landed
                "v_cmp_eq_u64 vcc, -1, %1\n\t"
                "s_cbranch_vccz 3f\n\t"
                "global_load_dwordx2 %1, %2, off sc1\n\t"
                "s_branch 1b\n\t"
                "2:\n\t"
                "ds_write_b64 %3, %0\n\t"
                "s_branch 4f\n\t"
                "3:\n\t"
                "ds_write_b64 %3, %1\n\t"
                "4:"
                : "+v"(pa), "+v"(pb)
                : "v"(p), "v"(dst)
                : "memory", "vcc");
        }
        __syncthreads();                       // B1: row t-1 staged

        const float* hb = &hbuf[q][seg * PAD];
        f32x2 p0 = {0.f, 0.f}, p1 = {0.f, 0.f}, p2 = {0.f, 0.f}, p3 = {0.f, 0.f};
#pragma unroll
        for (int k = 0; k < 16; ++k) {
            f32x4 h4 = *(const f32x4*)(hb + 4 * k);
            f32x4 wv = wreg[k];
            if ((k & 1) == 0) { pkfma(p0, wv.xy, h4.xy); pkfma(p1, wv.zw, h4.zw); }
            else              { pkfma(p2, wv.xy, h4.xy); pkfma(p3, wv.zw, h4.zw); }
        }
        f32x2 ps = (p0 + p1) + (p2 + p3);
        float a2 = ps.x + ps.y;
        a2 += __shfl_xor(a2, 1); a2 += __shfl_xor(a2, 2);
        a2 += __shfl_xor(a2, 4); a2 += __shfl_xor(a2, 8);

        // SENT(-NaN) torn-data backstop: NaN propagates into a2 for free.
        if (__builtin_expect(__any(a2 != a2), 0)) {
            // redo this wave's dot from global with per-dword-checked loads,
            // EXACT same accumulation order as the fast path.
            const unsigned* pp = (const unsigned*)hs + (size_t)(t - 1) * H + seg * 64;
            f32x2 r0 = {0.f,0.f}, r1 = {0.f,0.f}, r2 = {0.f,0.f}, r3 = {0.f,0.f};
            for (int k = 0; k < 16; ++k) {
                u32x4 v;
                for (;;) { v = load16_agent(pp + 4 * k); if (ok4(v)) break; }
                f32x4 h4;
                h4.x = __uint_as_float(v.x); h4.y = __uint_as_float(v.y);
                h4.z = __uint_as_float(v.z); h4.w = __uint_as_float(v.w);
                f32x4 wv = wreg[k];
                if ((k & 1) == 0) { pkfma(r0, wv.xy, h4.xy); pkfma(r1, wv.zw, h4.zw); }
                else              { pkfma(r2, wv.xy, h4.xy); pkfma(r3, wv.zw, h4.zw); }
            }
            f32x2 rs = (r0 + r1) + (r2 + r3);
            a2 = rs.x + rs.y;
            a2 += __shfl_xor(a2, 1); a2 += __shfl_xor(a2, 2);
            a2 += __shfl_xor(a2, 4); a2 += __shfl_xor(a2, 8);
        }

        float val = a2 + bias;
        float act = (g == 2) ? ftanh_(val) : fsig(val);   // parallel nonlinearity
        float si = __shfl(act, 0),  sf = __shfl(act, 16);
        float tg = __shfl(act, 32), so = __shfl(act, 48);
        float cn = sf * c_reg + si * tg;                  // wave-uniform cell
        float hn = so * ftanh_(cn);
        c_reg = cn;
        if (lane == 0) ((volatile unsigned*)h_out[q])[wave] = __float_as_uint(hn);
        if (wave == 15) {                      // gather + coalesced 64B store
            unsigned v;
            do { v = ((volatile unsigned*)h_out[q])[lane & 15]; } while (!__all(v != SENT));
            if (lane < 16) {
                __hip_atomic_store((unsigned*)(hs + (size_t)t * H) + wg * 16 + lane, v,
                                   __ATOMIC_RELAXED, __HIP_MEMORY_SCOPE_AGENT);
                ((volatile unsigned*)h_out[q])[lane] = SENT;   // reset for t+2
                hbuf[q ^ 1][(wg >> 2) * PAD + ((wg * 16) & 63) + lane] =
                    __uint_as_float(v);        // self-copy: skip own poll at t+1
            }
        }
    }

    // Drain any still-pending poll loads before pa/pb registers can be reused.
    asm volatile("s_waitcnt vmcnt(0)" :: "v"(pa), "v"(pb) : "memory");

    // ---- MLP tail: 4 groups x 256 threads (R5-proven, serial 16B polls) ----
    const int local = tid & 255;
    const int grp   = tid >> 8;      // 0..3
    const int row32 = local >> 3;    // 0..31
    const int sub   = local & 7;     // 0..7
    for (int ti = 0; ti < 8; ++ti) {
        int t = wg * 32 + ti * 4 + grp;
        __syncthreads();                       // WAR: prior mlp_buf/a_lds use
        {
            const unsigned* p = (const unsigned*)hs + (size_t)t * H + local * 4;
            u32x4 v;
            for (;;) {
                v = load16_agent(p);
                if (ok4(v)) break;
            }
            float* dst = &mlp_buf[grp][(local >> 4) * PAD + (local & 15) * 4];
            dst[0] = __uint_as_float(v.x); dst[1] = __uint_as_float(v.y);
            dst[2] = __uint_as_float(v.z); dst[3] = __uint_as_float(v.w);
        }
        __syncthreads();                       // row staged

        float acc1 = 0.f;
        const float* w1p = W1 + (size_t)row32 * H + sub * 128;
#pragma unroll
        for (int k = 0; k < 32; ++k) {
            float4 wv = *(const float4*)(w1p + 4 * k);
            int c = sub * 128 + 4 * k;
            float4 h4 = *(const float4*)(&mlp_buf[grp][(c >> 6) * PAD + (c & 63)]);
            acc1 += wv.x * h4.x + wv.y * h4.y + wv.z * h4.z + wv.w * h4.w;
        }
        acc1 += __shfl_xor(acc1, 1); acc1 += __shfl_xor(acc1, 2); acc1 += __shfl_xor(acc1, 4);
        if (sub == 0) a1_lds[grp][row32] = fmaxf(acc1 + b1[row32], 0.f);
        __syncthreads();                       // a1 ready

        if (local < 32) {
            float a = 0.f;
#pragma unroll
            for (int k = 0; k < 32; ++k) a += W2[local * 32 + k] * a1_lds[grp][k];
            a2_lds[grp][local] = fmaxf(a + b2[local], 0.f);
        }
        __syncthreads();                       // a2 ready

        if (local < 64) {
            float a = 0.f;
#pragma unroll
            for (int k = 0; k < 32; ++k) a += W3[local * 32 + k] * a2_lds[grp][k];
            out[(size_t)t * 64 + local] = a + b3[local];
        }
    }
}

extern "C" void kernel_launch(void* const* d_in, const int* in_sizes, int n_in,
                              void* d_out, int out_size, void* d_ws, size_t ws_size,
                              hipStream_t stream) {
    const float* z    = (const float*)d_in[0];
    const float* Wih  = (const float*)d_in[1];
    const float* Whh  = (const float*)d_in[2];
    const float* b_ih = (const float*)d_in[3];
    const float* b_hh = (const float*)d_in[4];
    const float* W1   = (const float*)d_in[5];
    const float* b1   = (const float*)d_in[6];
    const float* W2   = (const float*)d_in[7];
    const float* b2   = (const float*)d_in[8];
    const float* W3   = (const float*)d_in[9];
    const float* b3   = (const float*)d_in[10];
    float* out = (float*)d_out;

    float* hs = (float*)d_ws;   // TSTEPS*H floats = 8 MB, contiguous rows

    // Sentinel-fill hs: 0xFF bytes -> -NaN, unreachable as h.
    hipMemsetAsync(hs, 0xFF, (size_t)TSTEPS * H * sizeof(float), stream);
    hipLaunchKernelGGL(lstm_persistent, dim3(NWG), dim3(NT), 0, stream,
                       z, Wih, Whh, b_ih, b_hh, W1, b1, W2, b2, W3, b3,
                       out, hs);
}